// Round 8
// baseline (266003.394 us; speedup 1.0000x reference)
//
#include <hip/hip_runtime.h>
#include <math.h>

// HMM forward: alpha_t = (alpha_{t-1} @ A) * B[:, se[t]],  out = -log(sum(alpha_{T-1}))
// N_STATES=2048, N_OBS=8192, T=8192.
//
// Per-WAVE decomposition, zero LDS, zero __syncthreads in the main loop:
// 64 blk x 8 waves = 512 waves; wave gw owns output cols [4gw, 4gw+4).
// Lane L holds A[32L..32L+32)[c0..c0+4) in 128 regs and alpha[32L..32L+32)
// in 32 regs. Per step: 128 FMA -> 64-lane butterfly -> lanes 0..3 publish
// 4 tagged u64 packets {tag|f32} (agent-scope relaxed atomics) -> sentinel
// poll (8 loads/lane) -> one-shot 32-packet gather with tag verify.
// Dataflow (tags) enforces skew<=1, making the parity double-buffer safe.

#define NS    2048
#define NOBS  8192
#define TSEQ  8192
#define NBLK  64
#define NTHR  512

typedef unsigned long long u64;
typedef unsigned int u32;

#define L16A(X) X(0) X(1) X(2) X(3) X(4) X(5) X(6) X(7) \
                X(8) X(9) X(10) X(11) X(12) X(13) X(14) X(15)
#define L16B(X) X(16) X(17) X(18) X(19) X(20) X(21) X(22) X(23) \
                X(24) X(25) X(26) X(27) X(28) X(29) X(30) X(31)
#define L32(X) L16A(X) L16B(X)
#define L8(X)  X(0) X(1) X(2) X(3) X(4) X(5) X(6) X(7)

__global__ void __launch_bounds__(256) init_ws_kernel(u64* aP) {
  const int i = threadIdx.x;              // 1 block x 256 thr; 4096 u64 total
#pragma unroll
  for (int c = 0; c < 16; ++c) {
    __hip_atomic_store(&aP[i * 16 + c], 0ull, __ATOMIC_RELAXED, __HIP_MEMORY_SCOPE_AGENT);
  }
}

__global__ void __launch_bounds__(NTHR, 2) hmm_forward_kernel(
    const float* __restrict__ Pi0,
    const float* __restrict__ A,
    const float* __restrict__ B,
    const int*   __restrict__ se,
    float* __restrict__ out,
    u64*   __restrict__ aP) {            // [2][NS] tagged alpha packets
  const int tid  = threadIdx.x;
  const int blk  = blockIdx.x;
  const int w    = tid >> 6;
  const int lane = tid & 63;
  const int gw   = blk * 8 + w;          // global wave id 0..511
  const int c0   = gw * 4;               // owned output-column base
  const int jb   = lane * 32;            // lane's j-slice base

  // ---- A into 32 named float4 regs: Ar{k} = A[jb+k][c0..c0+3]
#define DECA(k) float4 Ar##k;
  L32(DECA)
#define LDA(k) Ar##k = *reinterpret_cast<const float4*>(A + (size_t)(jb + k) * NS + c0);
  L32(LDA)
#define PINA(k) asm volatile("" : "+v"(Ar##k.x), "+v"(Ar##k.y), "+v"(Ar##k.z), "+v"(Ar##k.w));
  L32(PINA)

  // ---- alpha_0 slice in 32 named regs (computed redundantly by every wave)
#define DECAL(k) float al##k;
  L32(DECAL)
  {
    const int s0v = se[0];
#define IAL(k) al##k = Pi0[jb + k] * B[(size_t)(jb + k) * NOBS + s0v];
    L32(IAL)
  }

  // emission prefetch for step 1 (lanes 0..3 own cols c0+lane)
  float bv = 0.f;
  if (lane < 4) bv = B[(size_t)(c0 + lane) * NOBS + se[1]];

  for (int t = 1; t < TSEQ; ++t) {
    const float bvc = bv;
    {  // prefetch emission for t+1; hides under compute+poll
      const int tn = (t + 1 < TSEQ) ? (t + 1) : t;
      const int sn = se[tn];
      if (lane < 4) bv = B[(size_t)(c0 + lane) * NOBS + sn];
    }

    __builtin_amdgcn_s_setprio(1);
    // ---- dot: 128 FMA in two chains per column
    float4 sA = {0.f, 0.f, 0.f, 0.f}, sB = {0.f, 0.f, 0.f, 0.f};
#define DOTA(k) { sA.x = fmaf(al##k, Ar##k.x, sA.x); sA.y = fmaf(al##k, Ar##k.y, sA.y); \
                  sA.z = fmaf(al##k, Ar##k.z, sA.z); sA.w = fmaf(al##k, Ar##k.w, sA.w); }
#define DOTB(k) { sB.x = fmaf(al##k, Ar##k.x, sB.x); sB.y = fmaf(al##k, Ar##k.y, sB.y); \
                  sB.z = fmaf(al##k, Ar##k.z, sB.z); sB.w = fmaf(al##k, Ar##k.w, sB.w); }
    L16A(DOTA) L16B(DOTB)
    float4 sv;
    sv.x = sA.x + sB.x; sv.y = sA.y + sB.y; sv.z = sA.z + sB.z; sv.w = sA.w + sB.w;
    // ---- 64-lane butterfly (all lanes end with full column sums)
#pragma unroll
    for (int off = 32; off; off >>= 1) {
      sv.x += __shfl_xor(sv.x, off);
      sv.y += __shfl_xor(sv.y, off);
      sv.z += __shfl_xor(sv.z, off);
      sv.w += __shfl_xor(sv.w, off);
    }

    // ---- publish 4 tagged packets (single vector store, lanes 0..3)
    u64* base = aP + (size_t)(t & 1) * NS;
    if (lane < 4) {
      const float vsel = (lane == 0) ? sv.x : (lane == 1) ? sv.y
                        : (lane == 2) ? sv.z : sv.w;
      const u64 pkt = (u64)__float_as_uint(vsel * bvc) | ((u64)(u32)t << 32);
      __hip_atomic_store(&base[c0 + lane], pkt, __ATOMIC_RELAXED, __HIP_MEMORY_SCOPE_AGENT);
    }
    __builtin_amdgcn_s_setprio(0);
    asm volatile("" ::: "memory");   // keep the store above the poll loop

    const u32 tt = (u32)t;
    // ---- phase 1: sentinel poll (last packet of each producer-wave quad)
    {
#define DECS(i) u64 sn##i;
      L8(DECS)
      for (;;) {
#define LSN(i) sn##i = __hip_atomic_load(&base[jb + 4 * i + 3], __ATOMIC_RELAXED, __HIP_MEMORY_SCOPE_AGENT);
        L8(LSN)
        const bool ok = ((u32)(sn0 >> 32) >= tt) & ((u32)(sn1 >> 32) >= tt) &
                        ((u32)(sn2 >> 32) >= tt) & ((u32)(sn3 >> 32) >= tt) &
                        ((u32)(sn4 >> 32) >= tt) & ((u32)(sn5 >> 32) >= tt) &
                        ((u32)(sn6 >> 32) >= tt) & ((u32)(sn7 >> 32) >= tt);
        if (__all(ok)) break;
      }
    }
    // ---- phase 2a: gather packets jb+0..15, verify tags, extract
    for (;;) {
#define DECQA(k) u64 q##k;
      L16A(DECQA)
#define LQA(k) q##k = __hip_atomic_load(&base[jb + k], __ATOMIC_RELAXED, __HIP_MEMORY_SCOPE_AGENT);
      L16A(LQA)
      const bool ok =
        ((u32)(q0  >> 32) >= tt) & ((u32)(q1  >> 32) >= tt) & ((u32)(q2  >> 32) >= tt) & ((u32)(q3  >> 32) >= tt) &
        ((u32)(q4  >> 32) >= tt) & ((u32)(q5  >> 32) >= tt) & ((u32)(q6  >> 32) >= tt) & ((u32)(q7  >> 32) >= tt) &
        ((u32)(q8  >> 32) >= tt) & ((u32)(q9  >> 32) >= tt) & ((u32)(q10 >> 32) >= tt) & ((u32)(q11 >> 32) >= tt) &
        ((u32)(q12 >> 32) >= tt) & ((u32)(q13 >> 32) >= tt) & ((u32)(q14 >> 32) >= tt) & ((u32)(q15 >> 32) >= tt);
      if (__all(ok)) {
#define XTA(k) al##k = __uint_as_float((u32)q##k);
        L16A(XTA)
        break;
      }
    }
    // ---- phase 2b: gather packets jb+16..31
    for (;;) {
#define DECQB(k) u64 q##k;
      L16B(DECQB)
#define LQB(k) q##k = __hip_atomic_load(&base[jb + k], __ATOMIC_RELAXED, __HIP_MEMORY_SCOPE_AGENT);
      L16B(LQB)
      const bool ok =
        ((u32)(q16 >> 32) >= tt) & ((u32)(q17 >> 32) >= tt) & ((u32)(q18 >> 32) >= tt) & ((u32)(q19 >> 32) >= tt) &
        ((u32)(q20 >> 32) >= tt) & ((u32)(q21 >> 32) >= tt) & ((u32)(q22 >> 32) >= tt) & ((u32)(q23 >> 32) >= tt) &
        ((u32)(q24 >> 32) >= tt) & ((u32)(q25 >> 32) >= tt) & ((u32)(q26 >> 32) >= tt) & ((u32)(q27 >> 32) >= tt) &
        ((u32)(q28 >> 32) >= tt) & ((u32)(q29 >> 32) >= tt) & ((u32)(q30 >> 32) >= tt) & ((u32)(q31 >> 32) >= tt);
      if (__all(ok)) {
#define XTB(k) al##k = __uint_as_float((u32)q##k);
        L16B(XTB)
        break;
      }
    }
  }

  // ---- final: -log(sum(alpha_{T-1})); wave 0 of block 0 holds a full copy
  if (blk == 0 && w == 0) {
    float s =
      (((al0  + al1 ) + (al2  + al3 )) + ((al4  + al5 ) + (al6  + al7 ))) +
      (((al8  + al9 ) + (al10 + al11)) + ((al12 + al13) + (al14 + al15))) +
      (((al16 + al17) + (al18 + al19)) + ((al20 + al21) + (al22 + al23))) +
      (((al24 + al25) + (al26 + al27)) + ((al28 + al29) + (al30 + al31)));
#pragma unroll
    for (int off = 32; off; off >>= 1) s += __shfl_xor(s, off);
    if (lane == 0) out[0] = -logf(s);
  }
}

extern "C" void kernel_launch(void* const* d_in, const int* in_sizes, int n_in,
                              void* d_out, int out_size, void* d_ws, size_t ws_size,
                              hipStream_t stream) {
  const float* Pi0 = (const float*)d_in[0];
  const float* A   = (const float*)d_in[1];
  const float* B   = (const float*)d_in[2];
  const int*   se  = (const int*)d_in[3];
  float*       out = (float*)d_out;

  // ws layout: aP = u64[2][NS] tagged alpha packets (32 KiB) at offset 0
  u64* aP = (u64*)d_ws;

  init_ws_kernel<<<1, 256, 0, stream>>>(aP);   // zero all tags (every launch)
  hmm_forward_kernel<<<NBLK, NTHR, 0, stream>>>(Pi0, A, B, se, out, aP);
}

// Round 9
// 49720.532 us; speedup vs baseline: 5.3500x; 5.3500x over previous
//
#include <hip/hip_runtime.h>
#include <math.h>

// HMM forward: alpha_t = (alpha_{t-1} @ A) * B[:, se[t]],  out = -log(sum(alpha_{T-1}))
// N_STATES=2048, N_OBS=8192, T=8192.
//
// 256 blocks x 128 threads (all 256 CUs busy). Block owns 8 output cols;
// thread owns j-slice [16t,16t+16) x 8 cols = 128 A-floats in named regs.
// Per step: dot from LDS alpha -> 64-lane butterfly -> cross-wave LDS reduce
// -> 8 tagged u64 packets {tag|f32} published (agent-scope relaxed atomics)
// -> block gathers all 2048 packets (16/thread, one-shot + tag-verify retry)
// into LDS. Tags enforce skew<=1 => parity double-buffer is safe.

#define NS    2048
#define NOBS  8192
#define TSEQ  8192
#define NBLK  256
#define NTHR  128
#define OPB   8               // output columns per block
#define JPT   16              // j per thread

typedef unsigned long long u64;
typedef unsigned int u32;

#define L16(X) X(0) X(1) X(2) X(3) X(4) X(5) X(6) X(7) \
               X(8) X(9) X(10) X(11) X(12) X(13) X(14) X(15)

__global__ void __launch_bounds__(256) init_ws_kernel(u64* aP) {
  const int i = threadIdx.x;              // 1 block x 256 thr; 4096 u64 total
#pragma unroll
  for (int c = 0; c < 16; ++c) {
    __hip_atomic_store(&aP[i * 16 + c], 0ull, __ATOMIC_RELAXED, __HIP_MEMORY_SCOPE_AGENT);
  }
}

__global__ void __launch_bounds__(NTHR, 2) hmm_forward_kernel(
    const float* __restrict__ Pi0,
    const float* __restrict__ A,
    const float* __restrict__ B,
    const int*   __restrict__ se,
    float* __restrict__ out,
    u64*   __restrict__ aP) {            // [2][NS] tagged alpha packets
  __shared__ __align__(16) float alpha_sm[NS];   // 8 KiB
  __shared__ float scratch[2 * OPB];             // cross-wave partials

  const int tid  = threadIdx.x;
  const int blk  = blockIdx.x;
  const int w    = tid >> 6;             // wave 0..1
  const int lane = tid & 63;
  const int c0   = blk * OPB;            // owned output-column base
  const int jb   = tid * JPT;            // thread's j-slice base

  // ---- A into 32 named float4 regs:
  //      ArA{k} = A[jb+k][c0..c0+3], ArB{k} = A[jb+k][c0+4..c0+7]
#define DECA(k) float4 ArA##k, ArB##k;
  L16(DECA)
#define LDA(k) { const float* ap = A + (size_t)(jb + k) * NS + c0; \
                 ArA##k = *reinterpret_cast<const float4*>(ap); \
                 ArB##k = *reinterpret_cast<const float4*>(ap + 4); }
  L16(LDA)
#define PINA(k) \
  asm volatile("" : "+v"(ArA##k.x), "+v"(ArA##k.y), "+v"(ArA##k.z), "+v"(ArA##k.w)); \
  asm volatile("" : "+v"(ArB##k.x), "+v"(ArB##k.y), "+v"(ArB##k.z), "+v"(ArB##k.w));
  L16(PINA)

  // ---- alpha_0 = Pi0 * B[:, se[0]] for this thread's 16 states
  {
    const int s0 = se[0];
#pragma unroll
    for (int k = 0; k < JPT; ++k) {
      alpha_sm[jb + k] = Pi0[jb + k] * B[(size_t)(jb + k) * NOBS + s0];
    }
  }
  __syncthreads();

  // emission prefetch for step 1 (threads 0..7 own cols c0+tid)
  float bv = 0.f;
  if (tid < OPB) bv = B[(size_t)(c0 + tid) * NOBS + se[1]];

  for (int t = 1; t < TSEQ; ++t) {
    const float bvc = bv;
    {  // prefetch emission for t+1
      const int tn = (t + 1 < TSEQ) ? (t + 1) : t;
      const int sn = se[tn];
      if (tid < OPB) bv = B[(size_t)(c0 + tid) * NOBS + sn];
    }

    // ---- dot: 128 FMA over j-slice [jb, jb+16) for 8 columns
    float4 acc0 = {0.f, 0.f, 0.f, 0.f}, acc1 = {0.f, 0.f, 0.f, 0.f};
#define DOT4(m) { \
      const float4 av = *reinterpret_cast<const float4*>(&alpha_sm[jb + 4 * m]); \
      { const float a = av.x; \
        acc0.x = fmaf(a, ArA##m##_0.x, acc0.x); } }
    // (expanded manually below; macro kept simple)
#undef DOT4
#define DOTE(k, comp) { const float a = comp; \
      acc0.x = fmaf(a, ArA##k.x, acc0.x); acc0.y = fmaf(a, ArA##k.y, acc0.y); \
      acc0.z = fmaf(a, ArA##k.z, acc0.z); acc0.w = fmaf(a, ArA##k.w, acc0.w); \
      acc1.x = fmaf(a, ArB##k.x, acc1.x); acc1.y = fmaf(a, ArB##k.y, acc1.y); \
      acc1.z = fmaf(a, ArB##k.z, acc1.z); acc1.w = fmaf(a, ArB##k.w, acc1.w); }
    {
      const float4 av0 = *reinterpret_cast<const float4*>(&alpha_sm[jb + 0]);
      DOTE(0, av0.x)  DOTE(1, av0.y)  DOTE(2, av0.z)  DOTE(3, av0.w)
      const float4 av1 = *reinterpret_cast<const float4*>(&alpha_sm[jb + 4]);
      DOTE(4, av1.x)  DOTE(5, av1.y)  DOTE(6, av1.z)  DOTE(7, av1.w)
      const float4 av2 = *reinterpret_cast<const float4*>(&alpha_sm[jb + 8]);
      DOTE(8, av2.x)  DOTE(9, av2.y)  DOTE(10, av2.z) DOTE(11, av2.w)
      const float4 av3 = *reinterpret_cast<const float4*>(&alpha_sm[jb + 12]);
      DOTE(12, av3.x) DOTE(13, av3.y) DOTE(14, av3.z) DOTE(15, av3.w)
    }

    // ---- butterfly over the 64-lane wave (8 sums, 6 hops)
#pragma unroll
    for (int off = 32; off; off >>= 1) {
      acc0.x += __shfl_xor(acc0.x, off); acc0.y += __shfl_xor(acc0.y, off);
      acc0.z += __shfl_xor(acc0.z, off); acc0.w += __shfl_xor(acc0.w, off);
      acc1.x += __shfl_xor(acc1.x, off); acc1.y += __shfl_xor(acc1.y, off);
      acc1.z += __shfl_xor(acc1.z, off); acc1.w += __shfl_xor(acc1.w, off);
    }
    if (lane < OPB) {
      const float v = (lane == 0) ? acc0.x : (lane == 1) ? acc0.y
                    : (lane == 2) ? acc0.z : (lane == 3) ? acc0.w
                    : (lane == 4) ? acc1.x : (lane == 5) ? acc1.y
                    : (lane == 6) ? acc1.z : acc1.w;
      scratch[w * OPB + lane] = v;
    }
    __syncthreads();   // partials ready; also: all alpha_sm reads of step t done

    // ---- threads 0..7: finish reduce, apply emission, publish tagged packet
    u64* base = aP + (size_t)(t & 1) * NS;
    if (tid < OPB) {
      const float s = scratch[tid] + scratch[OPB + tid];
      const u64 pkt = (u64)__float_as_uint(s * bvc) | ((u64)(u32)t << 32);
      __hip_atomic_store(&base[c0 + tid], pkt, __ATOMIC_RELAXED, __HIP_MEMORY_SCOPE_AGENT);
    }
    asm volatile("" ::: "memory");   // keep the publish above the gather

    // ---- gather all 2048 packets: 16 per thread, one-shot + verify-retry
    {
      const u32 tt = (u32)t;
      const u64* src = base + jb;
#define DECQ(k) u64 q##k;
      L16(DECQ)
      for (;;) {
#define LQ(k) q##k = __hip_atomic_load(&src[k], __ATOMIC_RELAXED, __HIP_MEMORY_SCOPE_AGENT);
        L16(LQ)
        const bool ok =
          ((u32)(q0  >> 32) >= tt) & ((u32)(q1  >> 32) >= tt) &
          ((u32)(q2  >> 32) >= tt) & ((u32)(q3  >> 32) >= tt) &
          ((u32)(q4  >> 32) >= tt) & ((u32)(q5  >> 32) >= tt) &
          ((u32)(q6  >> 32) >= tt) & ((u32)(q7  >> 32) >= tt) &
          ((u32)(q8  >> 32) >= tt) & ((u32)(q9  >> 32) >= tt) &
          ((u32)(q10 >> 32) >= tt) & ((u32)(q11 >> 32) >= tt) &
          ((u32)(q12 >> 32) >= tt) & ((u32)(q13 >> 32) >= tt) &
          ((u32)(q14 >> 32) >= tt) & ((u32)(q15 >> 32) >= tt);
        if (ok) break;
      }
      float4 v;
      v.x = __uint_as_float((u32)q0);  v.y = __uint_as_float((u32)q1);
      v.z = __uint_as_float((u32)q2);  v.w = __uint_as_float((u32)q3);
      *reinterpret_cast<float4*>(&alpha_sm[jb + 0]) = v;
      v.x = __uint_as_float((u32)q4);  v.y = __uint_as_float((u32)q5);
      v.z = __uint_as_float((u32)q6);  v.w = __uint_as_float((u32)q7);
      *reinterpret_cast<float4*>(&alpha_sm[jb + 4]) = v;
      v.x = __uint_as_float((u32)q8);  v.y = __uint_as_float((u32)q9);
      v.z = __uint_as_float((u32)q10); v.w = __uint_as_float((u32)q11);
      *reinterpret_cast<float4*>(&alpha_sm[jb + 8]) = v;
      v.x = __uint_as_float((u32)q12); v.y = __uint_as_float((u32)q13);
      v.z = __uint_as_float((u32)q14); v.w = __uint_as_float((u32)q15);
      *reinterpret_cast<float4*>(&alpha_sm[jb + 12]) = v;
    }
    __syncthreads();   // alpha_sm fully updated for next step
  }

  // ---- final: -log(sum(alpha_{T-1})), block 0 only (alpha is in its LDS)
  if (blk == 0) {
    float s = 0.f;
#pragma unroll
    for (int k = 0; k < JPT; ++k) s += alpha_sm[jb + k];
#pragma unroll
    for (int off = 32; off; off >>= 1) s += __shfl_xor(s, off);
    if (lane == 0) scratch[w] = s;
    __syncthreads();
    if (tid == 0) out[0] = -logf(scratch[0] + scratch[1]);
  }
}

extern "C" void kernel_launch(void* const* d_in, const int* in_sizes, int n_in,
                              void* d_out, int out_size, void* d_ws, size_t ws_size,
                              hipStream_t stream) {
  const float* Pi0 = (const float*)d_in[0];
  const float* A   = (const float*)d_in[1];
  const float* B   = (const float*)d_in[2];
  const int*   se  = (const int*)d_in[3];
  float*       out = (float*)d_out;

  // ws layout: aP = u64[2][NS] tagged alpha packets (32 KiB) at offset 0
  u64* aP = (u64*)d_ws;

  init_ws_kernel<<<1, 256, 0, stream>>>(aP);   // zero all tags (every launch)
  hmm_forward_kernel<<<NBLK, NTHR, 0, stream>>>(Pi0, A, B, se, out, aP);
}

// Round 10
// 17419.926 us; speedup vs baseline: 15.2701x; 2.8542x over previous
//
#include <hip/hip_runtime.h>
#include <math.h>

// HMM forward: alpha_t = (alpha_{t-1} @ A) * B[:, se[t]],  out = -log(sum(alpha_{T-1}))
// N_STATES=2048, N_OBS=8192, T=8192.
//
// Best-known structure (R5) + micro-opts:
// 64 blk x 512 thr. A in 128 f32 regs/thread (pinned; unified VGPR/AGPR file).
// Tagged-dataflow exchange: alpha published as u64 {tag:32|f32:32} agent-scope
// relaxed atomics (data==readiness, single LLC round trip); each wave polls and
// gathers only its own 256-float j-slice. ONE __syncthreads per step.
// This round: two-ahead se prefetch (B-emission row known at loop top),
// setprio around the reduce+publish critical section.

#define NS    2048
#define NOBS  8192
#define TSEQ  8192
#define NBLK  64
#define NTHR  512
#define OPB   32              // output columns per block
#define JPT   128             // j-slice length per thread

typedef unsigned long long u64;
typedef unsigned int u32;

// X-macro over the 32 float4 A-fragments
#define A_LIST(X) \
  X(0)  X(1)  X(2)  X(3)  X(4)  X(5)  X(6)  X(7)  \
  X(8)  X(9)  X(10) X(11) X(12) X(13) X(14) X(15) \
  X(16) X(17) X(18) X(19) X(20) X(21) X(22) X(23) \
  X(24) X(25) X(26) X(27) X(28) X(29) X(30) X(31)

__global__ void __launch_bounds__(256) init_ws_kernel(u64* aP) {
  const int i = threadIdx.x;              // 1 block x 256 thr; 4096 u64 total
#pragma unroll
  for (int c = 0; c < 16; ++c) {
    __hip_atomic_store(&aP[i * 16 + c], 0ull, __ATOMIC_RELAXED, __HIP_MEMORY_SCOPE_AGENT);
  }
}

__global__ void __launch_bounds__(NTHR, 2) hmm_forward_kernel(
    const float* __restrict__ Pi0,
    const float* __restrict__ A,
    const float* __restrict__ B,
    const int*   __restrict__ se,
    float* __restrict__ out,
    u64*   __restrict__ aP) {          // [2][NS] tagged alpha
  __shared__ __align__(16) float alpha_sm[NS];
  __shared__ float red[2][NTHR / 64][OPB];   // [parity][wave][o] (conflict-free)

  const int tid    = threadIdx.x;
  const int blk    = blockIdx.x;
  const int w      = tid >> 6;       // wave 0..7
  const int lane   = tid & 63;
  const int h      = lane >> 5;      // half-wave
  const int o      = lane & 31;      // output slot within block
  const int i_mine = blk * OPB + o;  // owned output column
  const int jbase  = (w * 2 + h) * JPT;

  // ---- A column-slice into 32 named float4 SSA registers:
  //      Ar{k} = A[jbase+4k .. jbase+4k+3][i_mine]
#define DECLA(k) float4 Ar##k;
  A_LIST(DECLA)
#define LOADA(k) { const float* ap = A + (size_t)(jbase + 4 * k) * NS + i_mine; \
                   Ar##k.x = ap[0]; Ar##k.y = ap[NS]; Ar##k.z = ap[2 * NS]; Ar##k.w = ap[3 * NS]; }
  A_LIST(LOADA)
  // Opaque pin: asm-defined scalars cannot be refolded/remat'd into the loop.
#define PIN4(k) asm volatile("" : "+v"(Ar##k.x), "+v"(Ar##k.y), "+v"(Ar##k.z), "+v"(Ar##k.w));
  A_LIST(PIN4)

  // ---- alpha_0 = Pi0 * B[:, se[0]], computed redundantly by every block
  {
    const int s0 = se[0];
#pragma unroll
    for (int c = 0; c < 4; ++c) {
      const int i = tid * 4 + c;
      alpha_sm[i] = Pi0[i] * B[(size_t)i * NOBS + s0];
    }
  }
  __syncthreads();

  // ---- emission prefetch pipeline (publishing lanes tid<32 only):
  // bv_next = B value for step 1; sidx_n2 = se row for step 2.
  float bv_next = 0.f;
  if (tid < OPB) bv_next = B[(size_t)i_mine * NOBS + se[1]];
  int sidx_n2 = se[2 < TSEQ ? 2 : TSEQ - 1];

  for (int t = 1; t < TSEQ; ++t) {
    const float bv  = bv_next;
    const int   buf = t & 1;
    // B row for step t+1 already known (sidx_n2) -> load issues immediately
    if (tid < OPB) bv_next = B[(size_t)i_mine * NOBS + sidx_n2];
    {  // se row for step t+2 (consumed next iteration; fully hidden)
      const int tn2 = (t + 2 < TSEQ) ? (t + 2) : (TSEQ - 1);
      sidx_n2 = se[tn2];
    }

    // ---- dot over this thread's 128-long j-slice (alpha from LDS, A in regs)
    float a0 = 0.f, a1 = 0.f, a2 = 0.f, a3 = 0.f;
#define DOT(k) { const float4 av = *reinterpret_cast<const float4*>(&alpha_sm[jbase + 4 * k]); \
                 a0 = fmaf(Ar##k.x, av.x, a0); a1 = fmaf(Ar##k.y, av.y, a1); \
                 a2 = fmaf(Ar##k.z, av.z, a2); a3 = fmaf(Ar##k.w, av.w, a3); }
    A_LIST(DOT)
    float acc = (a0 + a1) + (a2 + a3);
    acc += __shfl_xor(acc, 32);        // combine the two half-wave j-slices
    if (lane < 32) red[buf][w][o] = acc;
    __syncthreads();   // the ONE barrier per step: red[buf] handoff to wave 0

    // ---- wave 0: finish reduction, apply emission, publish tagged alpha_t
    if (w == 0) {
      __builtin_amdgcn_s_setprio(1);   // critical section vs polling waves
      float s = 0.f;
#pragma unroll
      for (int ww = 0; ww < NTHR / 64; ++ww) s += red[buf][ww][o];
      if (lane < 32) {
        const float aval = s * bv;
        const u64 pkt = (u64)__float_as_uint(aval) | ((u64)(u32)t << 32);
        __hip_atomic_store(&aP[(size_t)buf * NS + blk * OPB + o], pkt,
                           __ATOMIC_RELAXED, __HIP_MEMORY_SCOPE_AGENT);
      }
      __builtin_amdgcn_s_setprio(0);
    }

    // ---- each wave gathers ITS OWN 256-float j-slice by tag-poll
    // (data==readiness: one LLC round trip detects and delivers)
    {
      const u64* src = aP + (size_t)buf * NS + w * 256 + lane * 4;
      u64 q0, q1, q2, q3;
      const u32 tag = (u32)t;
      for (;;) {
        q0 = __hip_atomic_load(&src[0], __ATOMIC_RELAXED, __HIP_MEMORY_SCOPE_AGENT);
        q1 = __hip_atomic_load(&src[1], __ATOMIC_RELAXED, __HIP_MEMORY_SCOPE_AGENT);
        q2 = __hip_atomic_load(&src[2], __ATOMIC_RELAXED, __HIP_MEMORY_SCOPE_AGENT);
        q3 = __hip_atomic_load(&src[3], __ATOMIC_RELAXED, __HIP_MEMORY_SCOPE_AGENT);
        if ((u32)(q0 >> 32) == tag && (u32)(q1 >> 32) == tag &&
            (u32)(q2 >> 32) == tag && (u32)(q3 >> 32) == tag) break;
      }
      float4 v;
      v.x = __uint_as_float((u32)q0);
      v.y = __uint_as_float((u32)q1);
      v.z = __uint_as_float((u32)q2);
      v.w = __uint_as_float((u32)q3);
      *reinterpret_cast<float4*>(&alpha_sm[w * 256 + lane * 4]) = v;
    }
    // no barrier: next dot reads only this wave's own slice
  }

  // ---- final: -log(sum(alpha_{T-1})), block 0 only
  if (blk == 0) {
    __syncthreads();   // all waves' final gathers into alpha_sm
    float s = 0.f;
#pragma unroll
    for (int c = 0; c < 4; ++c) s += alpha_sm[4 * tid + c];
#pragma unroll
    for (int off = 32; off > 0; off >>= 1) s += __shfl_xor(s, off);
    if (lane == 0) red[0][w][0] = s;
    __syncthreads();
    if (tid == 0) {
      float S = 0.f;
#pragma unroll
      for (int ww = 0; ww < NTHR / 64; ++ww) S += red[0][ww][0];
      out[0] = -logf(S);
    }
  }
}

extern "C" void kernel_launch(void* const* d_in, const int* in_sizes, int n_in,
                              void* d_out, int out_size, void* d_ws, size_t ws_size,
                              hipStream_t stream) {
  const float* Pi0 = (const float*)d_in[0];
  const float* A   = (const float*)d_in[1];
  const float* B   = (const float*)d_in[2];
  const int*   se  = (const int*)d_in[3];
  float*       out = (float*)d_out;

  // ws layout: aP = u64[2][NS] tagged alpha packets (32 KiB) at offset 0
  u64* aP = (u64*)d_ws;

  init_ws_kernel<<<1, 256, 0, stream>>>(aP);   // zero all tags (every launch)
  hmm_forward_kernel<<<NBLK, NTHR, 0, stream>>>(Pi0, A, B, se, out, aP);
}